// Round 1
// baseline (270.861 us; speedup 1.0000x reference)
//
#include <hip/hip_runtime.h>
#include <stdint.h>

#define TT 2048
#define BB 2
#define MROWS (BB*TT)
#define SCALEF 0.125f

typedef unsigned short u16;
typedef __bf16 bf16x8 __attribute__((ext_vector_type(8)));
typedef float f32x4 __attribute__((ext_vector_type(4)));
typedef short s16x8 __attribute__((ext_vector_type(8)));
typedef unsigned short u16x4 __attribute__((ext_vector_type(4)));

#define GLOBAL_AS const __attribute__((address_space(1))) void*
#define LDS_AS __attribute__((address_space(3))) void*

__device__ __forceinline__ u16 f2b(float f){
  uint32_t u = __builtin_bit_cast(uint32_t, f);
  u = (u + 0x7FFFu + ((u >> 16) & 1u)) >> 16;
  return (u16)u;
}

// ---------------- prep kernels ----------------
__global__ void cvt_bf16(const float* __restrict__ in, u16* __restrict__ out, int n4){
  int i = blockIdx.x * 256 + threadIdx.x;
  if (i < n4){
    float4 v = ((const float4*)in)[i];
    u16x4 o; o.x = f2b(v.x); o.y = f2b(v.y); o.z = f2b(v.z); o.w = f2b(v.w);
    ((u16x4*)out)[i] = o;
  }
}

// Wqc[d][n] = sum_dd Wq[d][(n/64)*64+dd] * Wc[dd][n%64]   (fold Wc into Wq)
__global__ void build_wqc(const float* __restrict__ Wq, const float* __restrict__ Wc,
                          float* __restrict__ Wqc){
  int idx = blockIdx.x * 256 + threadIdx.x;    // 1M outputs
  int d = idx >> 10, n = idx & 1023, h = n >> 6, lc = n & 63;
  float acc = 0.f;
  #pragma unroll 8
  for (int dd = 0; dd < 64; ++dd)
    acc += Wq[d * 1024 + h * 64 + dd] * Wc[dd * 64 + lc];
  Wqc[idx] = acc;
}

__global__ void build_bqc(const float* __restrict__ bq, const float* __restrict__ Wc,
                          float* __restrict__ bqc){
  int n = blockIdx.x * 256 + threadIdx.x;
  int h = n >> 6, lc = n & 63;
  float acc = 0.f;
  for (int dd = 0; dd < 64; ++dd) acc += bq[h * 64 + dd] * Wc[dd * 64 + lc];
  bqc[n] = acc;
}

// out[c][r] = (bf16) in[r][c]   ; in is [R][C] f32
__global__ void transpose_to_bf16(const float* __restrict__ in, u16* __restrict__ out,
                                  int R, int C){
  __shared__ float t[32][33];
  int tx = threadIdx.x & 31, ty = threadIdx.x >> 5;
  int c0 = blockIdx.x * 32, r0 = blockIdx.y * 32;
  #pragma unroll
  for (int i = 0; i < 32; i += 8)
    t[ty + i][tx] = in[(size_t)(r0 + ty + i) * C + c0 + tx];
  __syncthreads();
  #pragma unroll
  for (int i = 0; i < 32; i += 8)
    out[(size_t)(c0 + ty + i) * R + r0 + tx] = f2b(t[tx][ty + i]);
}

// ---------------- 128x128 bf16 MFMA GEMM tile (m97 structure) ----------------
__device__ __forceinline__ void gemm_tile(const u16* __restrict__ A, const u16* __restrict__ BT,
                                          int m0, int n0, int K, f32x4 (&acc)[4][4],
                                          u16* As, u16* Bs, int tid){
  const int wv = tid >> 6, l = tid & 63;
  const int aoff = ((wv >> 1) * 64 + (l & 15)) * 32 + ((l >> 4) << 3);
  const int boff = ((wv & 1) * 64 + (l & 15)) * 32 + ((l >> 4) << 3);
  const int ob0 = wv * 1024 + l * 16;           // byte offset in 8KB tile
  for (int kt = 0; kt < K; kt += 32){
    __syncthreads();
    #pragma unroll
    for (int j = 0; j < 2; ++j){
      int ob = ob0 + j * 4096;
      int row = ob >> 6, col = (ob & 63) >> 1;  // col in elements (mult of 8)
      __builtin_amdgcn_global_load_lds((GLOBAL_AS)(A + (size_t)(m0 + row) * 1024 + kt + col),
                                       (LDS_AS)(As + wv * 512 + j * 2048), 16, 0, 0);
      __builtin_amdgcn_global_load_lds((GLOBAL_AS)(BT + (size_t)(n0 + row) * 1024 + kt + col),
                                       (LDS_AS)(Bs + wv * 512 + j * 2048), 16, 0, 0);
    }
    __syncthreads();
    bf16x8 av[4], bw[4];
    #pragma unroll
    for (int m = 0; m < 4; ++m) av[m] = *(const bf16x8*)(As + aoff + m * 512);
    #pragma unroll
    for (int n = 0; n < 4; ++n) bw[n] = *(const bf16x8*)(Bs + boff + n * 512);
    #pragma unroll
    for (int m = 0; m < 4; ++m)
      #pragma unroll
      for (int n = 0; n < 4; ++n)
        acc[m][n] = __builtin_amdgcn_mfma_f32_16x16x32_bf16(av[m], bw[n], acc[m][n], 0, 0, 0);
  }
}

__global__ __launch_bounds__(256) void gemm_qkv(
    const u16* __restrict__ xb,
    const u16* __restrict__ W0T, const u16* __restrict__ W1T, const u16* __restrict__ W2T,
    const float* __restrict__ b0, const float* __restrict__ b1, const float* __restrict__ b2,
    u16* __restrict__ o0, u16* __restrict__ o1, u16* __restrict__ o2){
  __shared__ u16 As[4096], Bs[4096];
  const int z = blockIdx.z;
  const u16* BT = (z == 0) ? W0T : (z == 1) ? W1T : W2T;
  const float* bias = (z == 0) ? b0 : (z == 1) ? b1 : b2;
  u16* Out = (z == 0) ? o0 : (z == 1) ? o1 : o2;
  const int n0 = blockIdx.x * 128, m0 = blockIdx.y * 128;
  const int tid = threadIdx.x, wv = tid >> 6, l = tid & 63;
  f32x4 acc[4][4] = {};
  gemm_tile(xb, BT, m0, n0, 1024, acc, As, Bs, tid);
  const int wr = wv >> 1, wc = wv & 1;
  #pragma unroll
  for (int n = 0; n < 4; ++n){
    int col = n0 + wc * 64 + n * 16 + (l & 15);
    float bb = bias[col];
    #pragma unroll
    for (int m = 0; m < 4; ++m){
      int r0 = m0 + wr * 64 + m * 16 + ((l >> 4) << 2);
      #pragma unroll
      for (int r = 0; r < 4; ++r)
        Out[(size_t)(r0 + r) * 1024 + col] = f2b(acc[m][n][r] + bb);
    }
  }
}

__global__ __launch_bounds__(256) void gemm_fp32out(
    const u16* __restrict__ A, const u16* __restrict__ BT,
    const float* __restrict__ bias, float* __restrict__ Out){
  __shared__ u16 As[4096], Bs[4096];
  const int n0 = blockIdx.x * 128, m0 = blockIdx.y * 128;
  const int tid = threadIdx.x, wv = tid >> 6, l = tid & 63;
  f32x4 acc[4][4] = {};
  gemm_tile(A, BT, m0, n0, 1024, acc, As, Bs, tid);
  const int wr = wv >> 1, wc = wv & 1;
  #pragma unroll
  for (int n = 0; n < 4; ++n){
    int col = n0 + wc * 64 + n * 16 + (l & 15);
    float bb = bias[col];
    #pragma unroll
    for (int m = 0; m < 4; ++m){
      int r0 = m0 + wr * 64 + m * 16 + ((l >> 4) << 2);
      #pragma unroll
      for (int r = 0; r < 4; ++r)
        Out[(size_t)(r0 + r) * 1024 + col] = acc[m][n][r] + bb;
    }
  }
}

// ---------------- flash attention (causal, per (b,h)) ----------------
// grid: x = q-tile (T/64 = 32), y = b*16+h (32). block 256 = 4 waves, 16 q-rows/wave.
__global__ __launch_bounds__(256) void attn(
    const u16* __restrict__ qcg, const u16* __restrict__ kg,
    const u16* __restrict__ vg, u16* __restrict__ yg){
  __shared__ u16 Ks[64 * 72], Vs[64 * 72], Ps[64 * 72];
  const int qt = blockIdx.x, bh = blockIdx.y;
  const int b = bh >> 4, h = bh & 15;
  const int q0 = qt * 64;
  const int tid = threadIdx.x, wv = tid >> 6, l = tid & 63;
  const size_t base = (size_t)b * TT * 1024 + h * 64;
  const u16* Q = qcg + base;
  const u16* K = kg + base;
  const u16* V = vg + base;

  // Q fragments in registers: A-operand rows = this wave's 16 q-rows
  bf16x8 qf[2];
  {
    int qr = q0 + wv * 16 + (l & 15);
    #pragma unroll
    for (int ks = 0; ks < 2; ++ks)
      qf[ks] = *(const bf16x8*)(Q + (size_t)qr * 1024 + ks * 32 + ((l >> 4) << 3));
  }
  f32x4 yacc[4] = {};
  float mrow[4], srow[4];
  #pragma unroll
  for (int r = 0; r < 4; ++r){ mrow[r] = -1e30f; srow[r] = 0.f; }

  const int nt = qt + 1;
  for (int st = 0; st < nt; ++st){
    const int s0 = st * 64;
    __syncthreads();
    // stage K (linear, padded rows) and V (transposed: Vs[d][s])
    #pragma unroll
    for (int i = 0; i < 2; ++i){
      int c = tid + i * 256;
      int s = c >> 3, c8 = c & 7;
      *(s16x8*)(Ks + s * 72 + c8 * 8) = *(const s16x8*)(K + (size_t)(s0 + s) * 1024 + c8 * 8);
      s16x8 vv8 = *(const s16x8*)(V + (size_t)(s0 + s) * 1024 + c8 * 8);
      #pragma unroll
      for (int j = 0; j < 8; ++j) Vs[(c8 * 8 + j) * 72 + s] = (u16)vv8[j];
    }
    __syncthreads();
    // S = Q K^T  (rows=q, cols=s)
    f32x4 sf[4] = {};
    #pragma unroll
    for (int ks = 0; ks < 2; ++ks)
      #pragma unroll
      for (int nf = 0; nf < 4; ++nf){
        bf16x8 kf = *(const bf16x8*)(Ks + (nf * 16 + (l & 15)) * 72 + ks * 32 + ((l >> 4) << 3));
        sf[nf] = __builtin_amdgcn_mfma_f32_16x16x32_bf16(qf[ks], kf, sf[nf], 0, 0, 0);
      }
    // scale + causal mask (only the diagonal tile needs it)
    float pv[4][4];
    const bool domask = (s0 == q0);
    #pragma unroll
    for (int nf = 0; nf < 4; ++nf)
      #pragma unroll
      for (int r = 0; r < 4; ++r){
        float v_ = sf[nf][r] * SCALEF;
        if (domask){
          int qq = wv * 16 + ((l >> 4) << 2) + r;
          int ss = nf * 16 + (l & 15);
          if (ss > qq) v_ = -1e30f;
        }
        pv[nf][r] = v_;
      }
    // online softmax per q-row (row owned by 16 lanes + 4 regs)
    #pragma unroll
    for (int r = 0; r < 4; ++r){
      float tmax = fmaxf(fmaxf(pv[0][r], pv[1][r]), fmaxf(pv[2][r], pv[3][r]));
      tmax = fmaxf(tmax, __shfl_xor(tmax, 1));
      tmax = fmaxf(tmax, __shfl_xor(tmax, 2));
      tmax = fmaxf(tmax, __shfl_xor(tmax, 4));
      tmax = fmaxf(tmax, __shfl_xor(tmax, 8));
      float mnew = fmaxf(mrow[r], tmax);
      float resc = __expf(mrow[r] - mnew);
      mrow[r] = mnew;
      float tsum = 0.f;
      #pragma unroll
      for (int nf = 0; nf < 4; ++nf){
        float p = __expf(pv[nf][r] - mnew);
        pv[nf][r] = p; tsum += p;
      }
      tsum += __shfl_xor(tsum, 1); tsum += __shfl_xor(tsum, 2);
      tsum += __shfl_xor(tsum, 4); tsum += __shfl_xor(tsum, 8);
      srow[r] = srow[r] * resc + tsum;
      #pragma unroll
      for (int df = 0; df < 4; ++df) yacc[df][r] *= resc;
    }
    // P -> LDS (intra-wave transpose for PV A-operand)
    #pragma unroll
    for (int nf = 0; nf < 4; ++nf)
      #pragma unroll
      for (int r = 0; r < 4; ++r)
        Ps[(wv * 16 + ((l >> 4) << 2) + r) * 72 + nf * 16 + (l & 15)] = f2b(pv[nf][r]);
    __syncthreads();   // ordering fence: P writes (b16) -> P reads (b128)
    // PV: y += P @ V
    #pragma unroll
    for (int ks2 = 0; ks2 < 2; ++ks2){
      bf16x8 pf = *(const bf16x8*)(Ps + (wv * 16 + (l & 15)) * 72 + ks2 * 32 + ((l >> 4) << 3));
      #pragma unroll
      for (int df = 0; df < 4; ++df){
        bf16x8 vf = *(const bf16x8*)(Vs + (df * 16 + (l & 15)) * 72 + ks2 * 32 + ((l >> 4) << 3));
        yacc[df] = __builtin_amdgcn_mfma_f32_16x16x32_bf16(pf, vf, yacc[df], 0, 0, 0);
      }
    }
  }
  // epilogue: y / srow -> yg[b*T+q][h*64+d]
  #pragma unroll
  for (int df = 0; df < 4; ++df){
    int d = df * 16 + (l & 15);
    int qq = q0 + wv * 16 + ((l >> 4) << 2);
    #pragma unroll
    for (int r = 0; r < 4; ++r){
      float val = yacc[df][r] / srow[r];
      yg[(size_t)(b * TT + qq + r) * 1024 + h * 64 + d] = f2b(val);
    }
  }
}

// ---------------- host ----------------
extern "C" void kernel_launch(void* const* d_in, const int* in_sizes, int n_in,
                              void* d_out, int out_size, void* d_ws, size_t ws_size,
                              hipStream_t stream){
  (void)in_sizes; (void)n_in; (void)out_size; (void)ws_size;
  const float* x  = (const float*)d_in[0];
  const float* Wq = (const float*)d_in[1];
  const float* bq = (const float*)d_in[2];
  const float* Wk = (const float*)d_in[3];
  const float* bk = (const float*)d_in[4];
  const float* Wv = (const float*)d_in[5];
  const float* bv = (const float*)d_in[6];
  const float* Wo = (const float*)d_in[7];
  const float* bo = (const float*)d_in[8];
  const float* Wc = (const float*)d_in[9];
  float* out = (float*)d_out;

  char* wsb = (char*)d_ws;
  u16* xb    = (u16*)(wsb);
  u16* qcb   = (u16*)(wsb + (8u  << 20));
  u16* kb    = (u16*)(wsb + (16u << 20));
  u16* vb    = (u16*)(wsb + (24u << 20));
  u16* yb    = (u16*)(wsb + (32u << 20));
  u16* WqcT  = (u16*)(wsb + (40u << 20));
  u16* WkT   = (u16*)(wsb + (42u << 20));
  u16* WvT   = (u16*)(wsb + (44u << 20));
  u16* WoT   = (u16*)(wsb + (46u << 20));
  float* bqc  = (float*)(wsb + (48u << 20));
  float* Wqcf = (float*)(wsb + (48u << 20) + 8192);

  cvt_bf16<<<4096, 256, 0, stream>>>(x, xb, MROWS * 1024 / 4);
  build_wqc<<<4096, 256, 0, stream>>>(Wq, Wc, Wqcf);
  build_bqc<<<4, 256, 0, stream>>>(bq, Wc, bqc);
  transpose_to_bf16<<<dim3(32, 32), 256, 0, stream>>>(Wqcf, WqcT, 1024, 1024);
  transpose_to_bf16<<<dim3(32, 32), 256, 0, stream>>>(Wk, WkT, 1024, 1024);
  transpose_to_bf16<<<dim3(32, 32), 256, 0, stream>>>(Wv, WvT, 1024, 1024);
  transpose_to_bf16<<<dim3(32, 32), 256, 0, stream>>>(Wo, WoT, 1024, 1024);
  gemm_qkv<<<dim3(8, 32, 3), 256, 0, stream>>>(xb, WqcT, WkT, WvT, bqc, bk, bv, qcb, kb, vb);
  attn<<<dim3(32, 32), 256, 0, stream>>>(qcb, kb, vb, yb);
  gemm_fp32out<<<dim3(8, 32), 256, 0, stream>>>(yb, WoT, bo, out);
}

// Round 2
// 171.035 us; speedup vs baseline: 1.5837x; 1.5837x over previous
//
#include <hip/hip_runtime.h>
#include <stdint.h>

#define TT 2048
#define BB 2
#define MROWS (BB*TT)
#define SCALEF 0.125f

typedef unsigned short u16;
typedef __bf16 bf16x8 __attribute__((ext_vector_type(8)));
typedef float f32x4 __attribute__((ext_vector_type(4)));
typedef short s16x8 __attribute__((ext_vector_type(8)));
typedef unsigned short u16x4 __attribute__((ext_vector_type(4)));

#define GLOBAL_AS const __attribute__((address_space(1))) void*
#define LDS_AS __attribute__((address_space(3))) void*

__device__ __forceinline__ u16 f2b(float f){
  uint32_t u = __builtin_bit_cast(uint32_t, f);
  u = (u + 0x7FFFu + ((u >> 16) & 1u)) >> 16;
  return (u16)u;
}

// ---------------- prep kernels ----------------
__global__ void cvt_bf16(const float* __restrict__ in, u16* __restrict__ out, int n4){
  int i = blockIdx.x * 256 + threadIdx.x;
  if (i < n4){
    float4 v = ((const float4*)in)[i];
    u16x4 o; o.x = f2b(v.x); o.y = f2b(v.y); o.z = f2b(v.z); o.w = f2b(v.w);
    ((u16x4*)out)[i] = o;
  }
}

// Wqc[d][n] = sum_dd Wq[d][(n/64)*64+dd] * Wc[dd][n%64]   (fold Wc into Wq)
__global__ void build_wqc(const float* __restrict__ Wq, const float* __restrict__ Wc,
                          float* __restrict__ Wqc){
  int idx = blockIdx.x * 256 + threadIdx.x;    // 1M outputs
  int d = idx >> 10, n = idx & 1023, h = n >> 6, lc = n & 63;
  float acc = 0.f;
  #pragma unroll 8
  for (int dd = 0; dd < 64; ++dd)
    acc += Wq[d * 1024 + h * 64 + dd] * Wc[dd * 64 + lc];
  Wqc[idx] = acc;
}

__global__ void build_bqc(const float* __restrict__ bq, const float* __restrict__ Wc,
                          float* __restrict__ bqc){
  int n = blockIdx.x * 256 + threadIdx.x;
  int h = n >> 6, lc = n & 63;
  float acc = 0.f;
  for (int dd = 0; dd < 64; ++dd) acc += bq[h * 64 + dd] * Wc[dd * 64 + lc];
  bqc[n] = acc;
}

// out[c][r] = (bf16) in[r][c]   ; in is [R][C] f32
__global__ void transpose_to_bf16(const float* __restrict__ in, u16* __restrict__ out,
                                  int R, int C){
  __shared__ float t[32][33];
  int tx = threadIdx.x & 31, ty = threadIdx.x >> 5;
  int c0 = blockIdx.x * 32, r0 = blockIdx.y * 32;
  #pragma unroll
  for (int i = 0; i < 32; i += 8)
    t[ty + i][tx] = in[(size_t)(r0 + ty + i) * C + c0 + tx];
  __syncthreads();
  #pragma unroll
  for (int i = 0; i < 32; i += 8)
    out[(size_t)(c0 + ty + i) * R + r0 + tx] = f2b(t[tx][ty + i]);
}

// vt[bh][d][s] = vb[b*T + s][h*64 + d]   (bf16 -> bf16 transpose per head)
__global__ void transpose_v(const u16* __restrict__ vb, u16* __restrict__ vt){
  __shared__ u16 t[32][34];
  int tx = threadIdx.x & 31, ty = threadIdx.x >> 5;
  int s0 = blockIdx.x * 32, d0 = blockIdx.y * 32, bh = blockIdx.z;
  int b = bh >> 4, h = bh & 15;
  #pragma unroll
  for (int i = 0; i < 32; i += 8)
    t[ty + i][tx] = vb[(size_t)(b * TT + s0 + ty + i) * 1024 + h * 64 + d0 + tx];
  __syncthreads();
  #pragma unroll
  for (int i = 0; i < 32; i += 8)
    vt[((size_t)bh * 64 + d0 + ty + i) * TT + s0 + tx] = t[tx][ty + i];
}

// ---------------- 128x128 bf16 MFMA GEMM tile (m97 structure) ----------------
__device__ __forceinline__ void gemm_tile(const u16* __restrict__ A, const u16* __restrict__ BT,
                                          int m0, int n0, int K, f32x4 (&acc)[4][4],
                                          u16* As, u16* Bs, int tid){
  const int wv = tid >> 6, l = tid & 63;
  const int aoff = ((wv >> 1) * 64 + (l & 15)) * 32 + ((l >> 4) << 3);
  const int boff = ((wv & 1) * 64 + (l & 15)) * 32 + ((l >> 4) << 3);
  const int ob0 = wv * 1024 + l * 16;           // byte offset in 8KB tile
  for (int kt = 0; kt < K; kt += 32){
    __syncthreads();
    #pragma unroll
    for (int j = 0; j < 2; ++j){
      int ob = ob0 + j * 4096;
      int row = ob >> 6, col = (ob & 63) >> 1;  // col in elements (mult of 8)
      __builtin_amdgcn_global_load_lds((GLOBAL_AS)(A + (size_t)(m0 + row) * 1024 + kt + col),
                                       (LDS_AS)(As + wv * 512 + j * 2048), 16, 0, 0);
      __builtin_amdgcn_global_load_lds((GLOBAL_AS)(BT + (size_t)(n0 + row) * 1024 + kt + col),
                                       (LDS_AS)(Bs + wv * 512 + j * 2048), 16, 0, 0);
    }
    __syncthreads();
    bf16x8 av[4], bw[4];
    #pragma unroll
    for (int m = 0; m < 4; ++m) av[m] = *(const bf16x8*)(As + aoff + m * 512);
    #pragma unroll
    for (int n = 0; n < 4; ++n) bw[n] = *(const bf16x8*)(Bs + boff + n * 512);
    #pragma unroll
    for (int m = 0; m < 4; ++m)
      #pragma unroll
      for (int n = 0; n < 4; ++n)
        acc[m][n] = __builtin_amdgcn_mfma_f32_16x16x32_bf16(av[m], bw[n], acc[m][n], 0, 0, 0);
  }
}

__global__ __launch_bounds__(256) void gemm_qkv(
    const u16* __restrict__ xb,
    const u16* __restrict__ W0T, const u16* __restrict__ W1T, const u16* __restrict__ W2T,
    const float* __restrict__ b0, const float* __restrict__ b1, const float* __restrict__ b2,
    u16* __restrict__ o0, u16* __restrict__ o1, u16* __restrict__ o2){
  __shared__ u16 As[4096], Bs[4096];
  const int z = blockIdx.z;
  const u16* BT = (z == 0) ? W0T : (z == 1) ? W1T : W2T;
  const float* bias = (z == 0) ? b0 : (z == 1) ? b1 : b2;
  u16* Out = (z == 0) ? o0 : (z == 1) ? o1 : o2;
  const int n0 = blockIdx.x * 128, m0 = blockIdx.y * 128;
  const int tid = threadIdx.x, wv = tid >> 6, l = tid & 63;
  f32x4 acc[4][4] = {};
  gemm_tile(xb, BT, m0, n0, 1024, acc, As, Bs, tid);
  const int wr = wv >> 1, wc = wv & 1;
  #pragma unroll
  for (int n = 0; n < 4; ++n){
    int col = n0 + wc * 64 + n * 16 + (l & 15);
    float bb = bias[col];
    #pragma unroll
    for (int m = 0; m < 4; ++m){
      int r0 = m0 + wr * 64 + m * 16 + ((l >> 4) << 2);
      #pragma unroll
      for (int r = 0; r < 4; ++r)
        Out[(size_t)(r0 + r) * 1024 + col] = f2b(acc[m][n][r] + bb);
    }
  }
}

__global__ __launch_bounds__(256) void gemm_fp32out(
    const u16* __restrict__ A, const u16* __restrict__ BT,
    const float* __restrict__ bias, float* __restrict__ Out){
  __shared__ u16 As[4096], Bs[4096];
  const int n0 = blockIdx.x * 128, m0 = blockIdx.y * 128;
  const int tid = threadIdx.x, wv = tid >> 6, l = tid & 63;
  f32x4 acc[4][4] = {};
  gemm_tile(A, BT, m0, n0, 1024, acc, As, Bs, tid);
  const int wr = wv >> 1, wc = wv & 1;
  #pragma unroll
  for (int n = 0; n < 4; ++n){
    int col = n0 + wc * 64 + n * 16 + (l & 15);
    float bb = bias[col];
    #pragma unroll
    for (int m = 0; m < 4; ++m){
      int r0 = m0 + wr * 64 + m * 16 + ((l >> 4) << 2);
      #pragma unroll
      for (int r = 0; r < 4; ++r)
        Out[(size_t)(r0 + r) * 1024 + col] = acc[m][n][r] + bb;
    }
  }
}

// ---------------- flash attention (causal, per (b,h)) ----------------
// BQ=128 (8 waves x 16 q-rows), BS=64. grid: 512 blocks linear, heavy-first.
__global__ __launch_bounds__(512) void attn(
    const u16* __restrict__ qcg, const u16* __restrict__ kg,
    const u16* __restrict__ vtg, u16* __restrict__ yg){
  __shared__ u16 Ks[4096], Vs[4096];   // [64 rows][8 chunks of 16B], XOR-swizzled
  __shared__ u16 Ps[128 * 72];
  const int idx = blockIdx.x;
  const int qt = 15 - (idx >> 5), bh = idx & 31;
  const int b = bh >> 4, h = bh & 15;
  const int q0 = qt * 128;
  const int tid = threadIdx.x, wv = tid >> 6, l = tid & 63;
  const size_t base = (size_t)b * TT * 1024 + h * 64;
  const u16* Q = qcg + base;
  const u16* K = kg + base;
  const u16* Vt = vtg + (size_t)bh * 64 * TT;     // [64 d][T s]

  // staging source (pre-swizzled so linear LDS == swizzled layout, m173 pattern)
  const int sr = tid >> 3;                         // tile row 0..63
  const int sc = (tid & 7) ^ (sr & 7);             // global 16B-chunk for this slot
  const u16* gK = K + (size_t)sr * 1024 + sc * 8;
  const u16* gV = Vt + (size_t)sr * TT + sc * 8;
  u16* ldsK = Ks + wv * 512;                       // wave-uniform dest
  u16* ldsV = Vs + wv * 512;

  // Q fragments in registers: 16 q-rows per wave
  bf16x8 qf[2];
  {
    int qr = q0 + wv * 16 + (l & 15);
    #pragma unroll
    for (int ks = 0; ks < 2; ++ks)
      qf[ks] = *(const bf16x8*)(Q + (size_t)qr * 1024 + ks * 32 + ((l >> 4) << 3));
  }
  f32x4 yacc[4] = {};
  float mrow[4], srow[4];
  #pragma unroll
  for (int r = 0; r < 4; ++r){ mrow[r] = -1e30f; srow[r] = 0.f; }

  const int nt = 2 * qt + 2;
  for (int st = 0; st < nt; ++st){
    const int s0 = st * 64;
    __syncthreads();
    __builtin_amdgcn_global_load_lds((GLOBAL_AS)(gK + (size_t)s0 * 1024), (LDS_AS)ldsK, 16, 0, 0);
    __builtin_amdgcn_global_load_lds((GLOBAL_AS)(gV + s0),                (LDS_AS)ldsV, 16, 0, 0);
    __syncthreads();
    // S = Q K^T  (rows=q, cols=s)
    f32x4 sf[4] = {};
    #pragma unroll
    for (int ks = 0; ks < 2; ++ks)
      #pragma unroll
      for (int nf = 0; nf < 4; ++nf){
        int r = nf * 16 + (l & 15), c = ks * 4 + (l >> 4);
        bf16x8 kf = *(const bf16x8*)(Ks + (r * 8 + (c ^ (r & 7))) * 8);
        sf[nf] = __builtin_amdgcn_mfma_f32_16x16x32_bf16(qf[ks], kf, sf[nf], 0, 0, 0);
      }
    // scale + causal mask (only tiles that cross this wave's diagonal)
    float pv[4][4];
    const bool domask = (s0 + 63 > q0 + wv * 16);
    #pragma unroll
    for (int nf = 0; nf < 4; ++nf)
      #pragma unroll
      for (int r = 0; r < 4; ++r){
        float v_ = sf[nf][r] * SCALEF;
        if (domask){
          int qq = q0 + wv * 16 + ((l >> 4) << 2) + r;
          int ss = s0 + nf * 16 + (l & 15);
          if (ss > qq) v_ = -1e30f;
        }
        pv[nf][r] = v_;
      }
    // online softmax per q-row (row owned by 16 lanes + 4 regs)
    #pragma unroll
    for (int r = 0; r < 4; ++r){
      float tmax = fmaxf(fmaxf(pv[0][r], pv[1][r]), fmaxf(pv[2][r], pv[3][r]));
      tmax = fmaxf(tmax, __shfl_xor(tmax, 1));
      tmax = fmaxf(tmax, __shfl_xor(tmax, 2));
      tmax = fmaxf(tmax, __shfl_xor(tmax, 4));
      tmax = fmaxf(tmax, __shfl_xor(tmax, 8));
      float mnew = fmaxf(mrow[r], tmax);
      float resc = __expf(mrow[r] - mnew);
      mrow[r] = mnew;
      float tsum = 0.f;
      #pragma unroll
      for (int nf = 0; nf < 4; ++nf){
        float p = __expf(pv[nf][r] - mnew);
        pv[nf][r] = p; tsum += p;
      }
      tsum += __shfl_xor(tsum, 1); tsum += __shfl_xor(tsum, 2);
      tsum += __shfl_xor(tsum, 4); tsum += __shfl_xor(tsum, 8);
      srow[r] = srow[r] * resc + tsum;
      #pragma unroll
      for (int df = 0; df < 4; ++df) yacc[df][r] *= resc;
    }
    // P -> LDS (wave-private rows; no cross-wave barrier needed)
    #pragma unroll
    for (int nf = 0; nf < 4; ++nf)
      #pragma unroll
      for (int r = 0; r < 4; ++r)
        Ps[(wv * 16 + ((l >> 4) << 2) + r) * 72 + nf * 16 + (l & 15)] = f2b(pv[nf][r]);
    asm volatile("s_waitcnt lgkmcnt(0)" ::: "memory");
    __builtin_amdgcn_sched_barrier(0);
    // PV: y += P @ V   (B-operand = V^T rows d)
    #pragma unroll
    for (int ks2 = 0; ks2 < 2; ++ks2){
      bf16x8 pf = *(const bf16x8*)(Ps + (wv * 16 + (l & 15)) * 72 + ks2 * 32 + ((l >> 4) << 3));
      #pragma unroll
      for (int df = 0; df < 4; ++df){
        int rd = df * 16 + (l & 15), cd = ks2 * 4 + (l >> 4);
        bf16x8 vf = *(const bf16x8*)(Vs + (rd * 8 + (cd ^ (rd & 7))) * 8);
        yacc[df] = __builtin_amdgcn_mfma_f32_16x16x32_bf16(pf, vf, yacc[df], 0, 0, 0);
      }
    }
  }
  // epilogue: y / srow -> yg[b*T+q][h*64+d]
  #pragma unroll
  for (int df = 0; df < 4; ++df){
    int d = df * 16 + (l & 15);
    int qq = q0 + wv * 16 + ((l >> 4) << 2);
    #pragma unroll
    for (int r = 0; r < 4; ++r){
      float val = yacc[df][r] / srow[r];
      yg[(size_t)(b * TT + qq + r) * 1024 + h * 64 + d] = f2b(val);
    }
  }
}

// ---------------- host ----------------
extern "C" void kernel_launch(void* const* d_in, const int* in_sizes, int n_in,
                              void* d_out, int out_size, void* d_ws, size_t ws_size,
                              hipStream_t stream){
  (void)in_sizes; (void)n_in; (void)out_size; (void)ws_size;
  const float* x  = (const float*)d_in[0];
  const float* Wq = (const float*)d_in[1];
  const float* bq = (const float*)d_in[2];
  const float* Wk = (const float*)d_in[3];
  const float* bk = (const float*)d_in[4];
  const float* Wv = (const float*)d_in[5];
  const float* bv = (const float*)d_in[6];
  const float* Wo = (const float*)d_in[7];
  const float* bo = (const float*)d_in[8];
  const float* Wc = (const float*)d_in[9];
  float* out = (float*)d_out;

  char* wsb = (char*)d_ws;
  u16* xb    = (u16*)(wsb);              // 8MB; dead after gemm_qkv
  u16* yb    = (u16*)(wsb);              // reuses xb region (written by attn, after)
  u16* qcb   = (u16*)(wsb + (8u  << 20));
  u16* kb    = (u16*)(wsb + (16u << 20));
  u16* vb    = (u16*)(wsb + (24u << 20));
  u16* vtb   = (u16*)(wsb + (32u << 20));
  u16* WqcT  = (u16*)(wsb + (40u << 20));
  u16* WkT   = (u16*)(wsb + (42u << 20));
  u16* WvT   = (u16*)(wsb + (44u << 20));
  u16* WoT   = (u16*)(wsb + (46u << 20));
  float* bqc  = (float*)(wsb + (48u << 20));
  float* Wqcf = (float*)(wsb + (48u << 20) + 8192);

  cvt_bf16<<<4096, 256, 0, stream>>>(x, xb, MROWS * 1024 / 4);
  build_wqc<<<4096, 256, 0, stream>>>(Wq, Wc, Wqcf);
  build_bqc<<<4, 256, 0, stream>>>(bq, Wc, bqc);
  transpose_to_bf16<<<dim3(32, 32), 256, 0, stream>>>(Wqcf, WqcT, 1024, 1024);
  transpose_to_bf16<<<dim3(32, 32), 256, 0, stream>>>(Wk, WkT, 1024, 1024);
  transpose_to_bf16<<<dim3(32, 32), 256, 0, stream>>>(Wv, WvT, 1024, 1024);
  transpose_to_bf16<<<dim3(32, 32), 256, 0, stream>>>(Wo, WoT, 1024, 1024);
  gemm_qkv<<<dim3(8, 32, 3), 256, 0, stream>>>(xb, WqcT, WkT, WvT, bqc, bk, bv, qcb, kb, vb);
  transpose_v<<<dim3(64, 2, 32), 256, 0, stream>>>(vb, vtb);
  attn<<<dim3(512), 512, 0, stream>>>(qcb, kb, vtb, yb);
  gemm_fp32out<<<dim3(8, 32), 256, 0, stream>>>(yb, WoT, bo, out);
}

// Round 3
// 158.532 us; speedup vs baseline: 1.7086x; 1.0789x over previous
//
#include <hip/hip_runtime.h>
#include <stdint.h>

#define TT 2048
#define BB 2
#define MROWS (BB*TT)
#define SCALEF 0.125f

typedef unsigned short u16;
typedef __bf16 bf16x8 __attribute__((ext_vector_type(8)));
typedef float f32x4 __attribute__((ext_vector_type(4)));
typedef short s16x8 __attribute__((ext_vector_type(8)));
typedef unsigned short u16x4 __attribute__((ext_vector_type(4)));

#define GLOBAL_AS const __attribute__((address_space(1))) void*
#define LDS_AS __attribute__((address_space(3))) void*

__device__ __forceinline__ u16 f2b(float f){
  uint32_t u = __builtin_bit_cast(uint32_t, f);
  u = (u + 0x7FFFu + ((u >> 16) & 1u)) >> 16;
  return (u16)u;
}

// ---------------- prep kernels ----------------
__global__ void cvt_bf16(const float* __restrict__ in, u16* __restrict__ out, int n4){
  int i = blockIdx.x * 256 + threadIdx.x;
  if (i < n4){
    float4 v = ((const float4*)in)[i];
    u16x4 o; o.x = f2b(v.x); o.y = f2b(v.y); o.z = f2b(v.z); o.w = f2b(v.w);
    ((u16x4*)out)[i] = o;
  }
}

// Wqc[d][h*64+lc] = sum_dd Wq[d][h*64+dd] * Wc[dd][lc]  (fold Wc into Wq)
// grid 256 x 256: thread handles (d, h, 16 lc)
__global__ __launch_bounds__(256) void build_wqc(const float* __restrict__ Wq,
                                                 const float* __restrict__ Wc,
                                                 float* __restrict__ Wqc){
  __shared__ float wc[4096];
  const int t = threadIdx.x;
  #pragma unroll
  for (int i = 0; i < 16; ++i) wc[i * 256 + t] = Wc[i * 256 + t];
  __syncthreads();
  const int idx = blockIdx.x * 256 + t;   // [0, 65536)
  const int d = idx >> 6;
  const int h = (idx >> 2) & 15;
  const int lq = idx & 3;
  float wqr[64];
  const float4* wq4 = (const float4*)(Wq + (size_t)d * 1024 + h * 64);
  #pragma unroll
  for (int i = 0; i < 16; ++i){
    float4 v = wq4[i];
    wqr[i * 4 + 0] = v.x; wqr[i * 4 + 1] = v.y; wqr[i * 4 + 2] = v.z; wqr[i * 4 + 3] = v.w;
  }
  float* outp = Wqc + (size_t)d * 1024 + h * 64 + lq * 16;
  #pragma unroll
  for (int j = 0; j < 16; ++j){
    int lc = lq * 16 + j;
    float acc = 0.f;
    #pragma unroll
    for (int dd = 0; dd < 64; ++dd) acc += wqr[dd] * wc[dd * 64 + lc];
    outp[j] = acc;
  }
}

__global__ void build_bqc(const float* __restrict__ bq, const float* __restrict__ Wc,
                          float* __restrict__ bqc){
  int n = blockIdx.x * 256 + threadIdx.x;
  int h = n >> 6, lc = n & 63;
  float acc = 0.f;
  for (int dd = 0; dd < 64; ++dd) acc += bq[h * 64 + dd] * Wc[dd * 64 + lc];
  bqc[n] = acc;
}

// all four 1024x1024 weight transposes (f32 -> bf16, out[c][r] = in[r][c]) in one dispatch
__global__ void transpose_w4(const float* __restrict__ s0, const float* __restrict__ s1,
                             const float* __restrict__ s2, const float* __restrict__ s3,
                             u16* __restrict__ o0, u16* __restrict__ o1,
                             u16* __restrict__ o2, u16* __restrict__ o3){
  const int z = blockIdx.z;
  const float* in = (z == 0) ? s0 : (z == 1) ? s1 : (z == 2) ? s2 : s3;
  u16* out = (z == 0) ? o0 : (z == 1) ? o1 : (z == 2) ? o2 : o3;
  __shared__ float t[32][33];
  int tx = threadIdx.x & 31, ty = threadIdx.x >> 5;
  int c0 = blockIdx.x * 32, r0 = blockIdx.y * 32;
  #pragma unroll
  for (int i = 0; i < 32; i += 8)
    t[ty + i][tx] = in[(size_t)(r0 + ty + i) * 1024 + c0 + tx];
  __syncthreads();
  #pragma unroll
  for (int i = 0; i < 32; i += 8)
    out[(size_t)(c0 + ty + i) * 1024 + r0 + tx] = f2b(t[tx][ty + i]);
}

// vt[bh][d][s] = vb[b*T + s][h*64 + d]   (bf16 -> bf16 transpose per head)
__global__ void transpose_v(const u16* __restrict__ vb, u16* __restrict__ vt){
  __shared__ u16 t[32][34];
  int tx = threadIdx.x & 31, ty = threadIdx.x >> 5;
  int s0 = blockIdx.x * 32, d0 = blockIdx.y * 32, bh = blockIdx.z;
  int b = bh >> 4, h = bh & 15;
  #pragma unroll
  for (int i = 0; i < 32; i += 8)
    t[ty + i][tx] = vb[(size_t)(b * TT + s0 + ty + i) * 1024 + h * 64 + d0 + tx];
  __syncthreads();
  #pragma unroll
  for (int i = 0; i < 32; i += 8)
    vt[((size_t)bh * 64 + d0 + ty + i) * TT + s0 + tx] = t[tx][ty + i];
}

// ---------------- 128x128 bf16 MFMA GEMM tile (m97 structure) ----------------
__device__ __forceinline__ void gemm_tile(const u16* __restrict__ A, const u16* __restrict__ BT,
                                          int m0, int n0, int K, f32x4 (&acc)[4][4],
                                          u16* As, u16* Bs, int tid){
  const int wv = tid >> 6, l = tid & 63;
  const int aoff = ((wv >> 1) * 64 + (l & 15)) * 32 + ((l >> 4) << 3);
  const int boff = ((wv & 1) * 64 + (l & 15)) * 32 + ((l >> 4) << 3);
  const int ob0 = wv * 1024 + l * 16;           // byte offset in 8KB tile
  for (int kt = 0; kt < K; kt += 32){
    __syncthreads();
    #pragma unroll
    for (int j = 0; j < 2; ++j){
      int ob = ob0 + j * 4096;
      int row = ob >> 6, col = (ob & 63) >> 1;  // col in elements (mult of 8)
      __builtin_amdgcn_global_load_lds((GLOBAL_AS)(A + (size_t)(m0 + row) * 1024 + kt + col),
                                       (LDS_AS)(As + wv * 512 + j * 2048), 16, 0, 0);
      __builtin_amdgcn_global_load_lds((GLOBAL_AS)(BT + (size_t)(n0 + row) * 1024 + kt + col),
                                       (LDS_AS)(Bs + wv * 512 + j * 2048), 16, 0, 0);
    }
    __syncthreads();
    bf16x8 av[4], bw[4];
    #pragma unroll
    for (int m = 0; m < 4; ++m) av[m] = *(const bf16x8*)(As + aoff + m * 512);
    #pragma unroll
    for (int n = 0; n < 4; ++n) bw[n] = *(const bf16x8*)(Bs + boff + n * 512);
    #pragma unroll
    for (int m = 0; m < 4; ++m)
      #pragma unroll
      for (int n = 0; n < 4; ++n)
        acc[m][n] = __builtin_amdgcn_mfma_f32_16x16x32_bf16(av[m], bw[n], acc[m][n], 0, 0, 0);
  }
}

__global__ __launch_bounds__(256) void gemm_qkv(
    const u16* __restrict__ xb,
    const u16* __restrict__ W0T, const u16* __restrict__ W1T, const u16* __restrict__ W2T,
    const float* __restrict__ b0, const float* __restrict__ b1, const float* __restrict__ b2,
    u16* __restrict__ o0, u16* __restrict__ o1, u16* __restrict__ o2){
  __shared__ u16 As[4096], Bs[4096];
  const int z = blockIdx.z;
  const u16* BT = (z == 0) ? W0T : (z == 1) ? W1T : W2T;
  const float* bias = (z == 0) ? b0 : (z == 1) ? b1 : b2;
  u16* Out = (z == 0) ? o0 : (z == 1) ? o1 : o2;
  const int n0 = blockIdx.x * 128, m0 = blockIdx.y * 128;
  const int tid = threadIdx.x, wv = tid >> 6, l = tid & 63;
  f32x4 acc[4][4] = {};
  gemm_tile(xb, BT, m0, n0, 1024, acc, As, Bs, tid);
  const int wr = wv >> 1, wc = wv & 1;
  #pragma unroll
  for (int n = 0; n < 4; ++n){
    int col = n0 + wc * 64 + n * 16 + (l & 15);
    float bb = bias[col];
    #pragma unroll
    for (int m = 0; m < 4; ++m){
      int r0 = m0 + wr * 64 + m * 16 + ((l >> 4) << 2);
      #pragma unroll
      for (int r = 0; r < 4; ++r)
        Out[(size_t)(r0 + r) * 1024 + col] = f2b(acc[m][n][r] + bb);
    }
  }
}

__global__ __launch_bounds__(256) void gemm_fp32out(
    const u16* __restrict__ A, const u16* __restrict__ BT,
    const float* __restrict__ bias, float* __restrict__ Out){
  __shared__ u16 As[4096], Bs[4096];
  const int n0 = blockIdx.x * 128, m0 = blockIdx.y * 128;
  const int tid = threadIdx.x, wv = tid >> 6, l = tid & 63;
  f32x4 acc[4][4] = {};
  gemm_tile(A, BT, m0, n0, 1024, acc, As, Bs, tid);
  const int wr = wv >> 1, wc = wv & 1;
  #pragma unroll
  for (int n = 0; n < 4; ++n){
    int col = n0 + wc * 64 + n * 16 + (l & 15);
    float bb = bias[col];
    #pragma unroll
    for (int m = 0; m < 4; ++m){
      int r0 = m0 + wr * 64 + m * 16 + ((l >> 4) << 2);
      #pragma unroll
      for (int r = 0; r < 4; ++r)
        Out[(size_t)(r0 + r) * 1024 + col] = acc[m][n][r] + bb;
    }
  }
}

// ---------------- flash attention (causal, per (b,h)) ----------------
// BQ=128 (8 waves x 16 q-rows), BS=64, double-buffered staging with counted vmcnt.
// grid: 512 blocks linear, heavy-first.
__global__ __launch_bounds__(512) void attn(
    const u16* __restrict__ qcg, const u16* __restrict__ kg,
    const u16* __restrict__ vtg, u16* __restrict__ yg){
  __shared__ u16 Ks[2][4096], Vs[2][4096];   // [64 rows][8 chunks of 16B], XOR-swizzled
  __shared__ u16 Ps[128 * 72];
  const int idx = blockIdx.x;
  const int qt = 15 - (idx >> 5), bh = idx & 31;
  const int b = bh >> 4, h = bh & 15;
  const int q0 = qt * 128;
  const int tid = threadIdx.x, wv = tid >> 6, l = tid & 63;
  const size_t base = (size_t)b * TT * 1024 + h * 64;
  const u16* Q = qcg + base;
  const u16* K = kg + base;
  const u16* Vt = vtg + (size_t)bh * 64 * TT;     // [64 d][T s]

  // staging source (pre-swizzled so linear LDS == swizzled layout, m173 pattern)
  const int sr = tid >> 3;                         // tile row 0..63
  const int sc = (tid & 7) ^ (sr & 7);             // global 16B-chunk for this slot
  const u16* gK = K + (size_t)sr * 1024 + sc * 8;
  const u16* gV = Vt + (size_t)sr * TT + sc * 8;

  // prologue: stage tile 0 into buffer 0
  __builtin_amdgcn_global_load_lds((GLOBAL_AS)gK, (LDS_AS)(&Ks[0][0] + wv * 512), 16, 0, 0);
  __builtin_amdgcn_global_load_lds((GLOBAL_AS)gV, (LDS_AS)(&Vs[0][0] + wv * 512), 16, 0, 0);

  // Q fragments in registers: 16 q-rows per wave
  bf16x8 qf[2];
  {
    int qr = q0 + wv * 16 + (l & 15);
    #pragma unroll
    for (int ks = 0; ks < 2; ++ks)
      qf[ks] = *(const bf16x8*)(Q + (size_t)qr * 1024 + ks * 32 + ((l >> 4) << 3));
  }
  f32x4 yacc[4] = {};
  float mrow[4], srow[4];
  #pragma unroll
  for (int r = 0; r < 4; ++r){ mrow[r] = -1e30f; srow[r] = 0.f; }

  const int nt = 2 * qt + 2;
  for (int st = 0; st < nt; ++st){
    const int cur = st & 1;
    const u16* Kc = &Ks[cur][0];
    const u16* Vc = &Vs[cur][0];
    // prefetch next tile into the other buffer (its readers retired at prev end-barrier)
    if (st + 1 < nt){
      const int s1 = (st + 1) * 64;
      __builtin_amdgcn_global_load_lds((GLOBAL_AS)(gK + (size_t)s1 * 1024),
                                       (LDS_AS)(&Ks[cur ^ 1][0] + wv * 512), 16, 0, 0);
      __builtin_amdgcn_global_load_lds((GLOBAL_AS)(gV + s1),
                                       (LDS_AS)(&Vs[cur ^ 1][0] + wv * 512), 16, 0, 0);
      asm volatile("s_waitcnt vmcnt(2)" ::: "memory");   // cur's loads landed, next's in flight
    } else {
      asm volatile("s_waitcnt vmcnt(0)" ::: "memory");
    }
    __builtin_amdgcn_sched_barrier(0);
    __builtin_amdgcn_s_barrier();                         // all waves' cur loads landed
    __builtin_amdgcn_sched_barrier(0);
    const int s0 = st * 64;
    // S = Q K^T  (rows=q, cols=s)
    f32x4 sf[4] = {};
    __builtin_amdgcn_s_setprio(1);
    #pragma unroll
    for (int ks = 0; ks < 2; ++ks)
      #pragma unroll
      for (int nf = 0; nf < 4; ++nf){
        int r = nf * 16 + (l & 15), c = ks * 4 + (l >> 4);
        bf16x8 kf = *(const bf16x8*)(Kc + (r * 8 + (c ^ (r & 7))) * 8);
        sf[nf] = __builtin_amdgcn_mfma_f32_16x16x32_bf16(qf[ks], kf, sf[nf], 0, 0, 0);
      }
    __builtin_amdgcn_s_setprio(0);
    // scale + causal mask (only tiles that cross this wave's diagonal)
    float pv[4][4];
    const bool domask = (s0 + 63 > q0 + wv * 16);
    #pragma unroll
    for (int nf = 0; nf < 4; ++nf)
      #pragma unroll
      for (int r = 0; r < 4; ++r){
        float v_ = sf[nf][r] * SCALEF;
        if (domask){
          int qq = q0 + wv * 16 + ((l >> 4) << 2) + r;
          int ss = s0 + nf * 16 + (l & 15);
          if (ss > qq) v_ = -1e30f;
        }
        pv[nf][r] = v_;
      }
    // online softmax per q-row (row owned by 16 lanes + 4 regs)
    #pragma unroll
    for (int r = 0; r < 4; ++r){
      float tmax = fmaxf(fmaxf(pv[0][r], pv[1][r]), fmaxf(pv[2][r], pv[3][r]));
      tmax = fmaxf(tmax, __shfl_xor(tmax, 1));
      tmax = fmaxf(tmax, __shfl_xor(tmax, 2));
      tmax = fmaxf(tmax, __shfl_xor(tmax, 4));
      tmax = fmaxf(tmax, __shfl_xor(tmax, 8));
      float mnew = fmaxf(mrow[r], tmax);
      float resc = __expf(mrow[r] - mnew);
      mrow[r] = mnew;
      float tsum = 0.f;
      #pragma unroll
      for (int nf = 0; nf < 4; ++nf){
        float p = __expf(pv[nf][r] - mnew);
        pv[nf][r] = p; tsum += p;
      }
      tsum += __shfl_xor(tsum, 1); tsum += __shfl_xor(tsum, 2);
      tsum += __shfl_xor(tsum, 4); tsum += __shfl_xor(tsum, 8);
      srow[r] = srow[r] * resc + tsum;
      #pragma unroll
      for (int df = 0; df < 4; ++df) yacc[df][r] *= resc;
    }
    // P -> LDS (wave-private rows; intra-wave ordering only)
    #pragma unroll
    for (int nf = 0; nf < 4; ++nf)
      #pragma unroll
      for (int r = 0; r < 4; ++r)
        Ps[(wv * 16 + ((l >> 4) << 2) + r) * 72 + nf * 16 + (l & 15)] = f2b(pv[nf][r]);
    asm volatile("s_waitcnt lgkmcnt(0)" ::: "memory");
    __builtin_amdgcn_sched_barrier(0);
    // PV: y += P @ V   (B-operand = V^T rows d)
    __builtin_amdgcn_s_setprio(1);
    #pragma unroll
    for (int ks2 = 0; ks2 < 2; ++ks2){
      bf16x8 pf = *(const bf16x8*)(Ps + (wv * 16 + (l & 15)) * 72 + ks2 * 32 + ((l >> 4) << 3));
      #pragma unroll
      for (int df = 0; df < 4; ++df){
        int rd = df * 16 + (l & 15), cd = ks2 * 4 + (l >> 4);
        bf16x8 vf = *(const bf16x8*)(Vc + (rd * 8 + (cd ^ (rd & 7))) * 8);
        yacc[df] = __builtin_amdgcn_mfma_f32_16x16x32_bf16(pf, vf, yacc[df], 0, 0, 0);
      }
    }
    __builtin_amdgcn_s_setprio(0);
    __builtin_amdgcn_s_barrier();                         // all waves done reading cur bufs
  }
  // epilogue: y / srow -> yg[b*T+q][h*64+d]
  #pragma unroll
  for (int df = 0; df < 4; ++df){
    int d = df * 16 + (l & 15);
    int qq = q0 + wv * 16 + ((l >> 4) << 2);
    #pragma unroll
    for (int r = 0; r < 4; ++r){
      float val = yacc[df][r] / srow[r];
      yg[(size_t)(b * TT + qq + r) * 1024 + h * 64 + d] = f2b(val);
    }
  }
}

// ---------------- host ----------------
extern "C" void kernel_launch(void* const* d_in, const int* in_sizes, int n_in,
                              void* d_out, int out_size, void* d_ws, size_t ws_size,
                              hipStream_t stream){
  (void)in_sizes; (void)n_in; (void)out_size; (void)ws_size;
  const float* x  = (const float*)d_in[0];
  const float* Wq = (const float*)d_in[1];
  const float* bq = (const float*)d_in[2];
  const float* Wk = (const float*)d_in[3];
  const float* bk = (const float*)d_in[4];
  const float* Wv = (const float*)d_in[5];
  const float* bv = (const float*)d_in[6];
  const float* Wo = (const float*)d_in[7];
  const float* bo = (const float*)d_in[8];
  const float* Wc = (const float*)d_in[9];
  float* out = (float*)d_out;

  char* wsb = (char*)d_ws;
  u16* xb    = (u16*)(wsb);              // 8MB; dead after gemm_qkv
  u16* yb    = (u16*)(wsb);              // reuses xb region (written by attn, after)
  u16* qcb   = (u16*)(wsb + (8u  << 20));
  u16* kb    = (u16*)(wsb + (16u << 20));
  u16* vb    = (u16*)(wsb + (24u << 20));
  u16* vtb   = (u16*)(wsb + (32u << 20));
  u16* WqcT  = (u16*)(wsb + (40u << 20));
  u16* WkT   = (u16*)(wsb + (42u << 20));
  u16* WvT   = (u16*)(wsb + (44u << 20));
  u16* WoT   = (u16*)(wsb + (46u << 20));
  float* bqc  = (float*)(wsb + (48u << 20));
  float* Wqcf = (float*)(wsb + (48u << 20) + 8192);

  cvt_bf16<<<4096, 256, 0, stream>>>(x, xb, MROWS * 1024 / 4);
  build_wqc<<<256, 256, 0, stream>>>(Wq, Wc, Wqcf);
  build_bqc<<<4, 256, 0, stream>>>(bq, Wc, bqc);
  transpose_w4<<<dim3(32, 32, 4), 256, 0, stream>>>(Wqcf, Wk, Wv, Wo, WqcT, WkT, WvT, WoT);
  gemm_qkv<<<dim3(8, 32, 3), 256, 0, stream>>>(xb, WqcT, WkT, WvT, bqc, bk, bv, qcb, kb, vb);
  transpose_v<<<dim3(64, 2, 32), 256, 0, stream>>>(vb, vtb);
  attn<<<dim3(512), 512, 0, stream>>>(qcb, kb, vtb, yb);
  gemm_fp32out<<<dim3(8, 32), 256, 0, stream>>>(yb, WoT, bo, out);
}

// Round 4
// 140.947 us; speedup vs baseline: 1.9217x; 1.1248x over previous
//
#include <hip/hip_runtime.h>
#include <stdint.h>

#define TT 2048
#define BB 2
#define MROWS (BB*TT)
#define SCALEF 0.125f
#define LSCALE 0.18033688011112043f   // 0.125 * log2(e)

typedef unsigned short u16;
typedef __bf16 bf16x8 __attribute__((ext_vector_type(8)));
typedef float f32x4 __attribute__((ext_vector_type(4)));
typedef short s16x8 __attribute__((ext_vector_type(8)));
typedef unsigned short u16x4 __attribute__((ext_vector_type(4)));

#define GLOBAL_AS const __attribute__((address_space(1))) void*
#define LDS_AS __attribute__((address_space(3))) void*

__device__ __forceinline__ u16 f2b(float f){
  uint32_t u = __builtin_bit_cast(uint32_t, f);
  u = (u + 0x7FFFu + ((u >> 16) & 1u)) >> 16;
  return (u16)u;
}

// ---------------- prep kernels ----------------
__global__ void cvt_bf16(const float* __restrict__ in, u16* __restrict__ out, int n4){
  int i = blockIdx.x * 256 + threadIdx.x;
  if (i < n4){
    float4 v = ((const float4*)in)[i];
    u16x4 o; o.x = f2b(v.x); o.y = f2b(v.y); o.z = f2b(v.z); o.w = f2b(v.w);
    ((u16x4*)out)[i] = o;
  }
}

// Wqc[d][h*64+lc] = sum_dd Wq[d][h*64+dd] * Wc[dd][lc]  (fold Wc into Wq)
__global__ __launch_bounds__(256) void build_wqc(const float* __restrict__ Wq,
                                                 const float* __restrict__ Wc,
                                                 float* __restrict__ Wqc){
  __shared__ float wc[4096];
  const int t = threadIdx.x;
  #pragma unroll
  for (int i = 0; i < 16; ++i) wc[i * 256 + t] = Wc[i * 256 + t];
  __syncthreads();
  const int idx = blockIdx.x * 256 + t;   // [0, 65536)
  const int d = idx >> 6;
  const int h = (idx >> 2) & 15;
  const int lq = idx & 3;
  float wqr[64];
  const float4* wq4 = (const float4*)(Wq + (size_t)d * 1024 + h * 64);
  #pragma unroll
  for (int i = 0; i < 16; ++i){
    float4 v = wq4[i];
    wqr[i * 4 + 0] = v.x; wqr[i * 4 + 1] = v.y; wqr[i * 4 + 2] = v.z; wqr[i * 4 + 3] = v.w;
  }
  float* outp = Wqc + (size_t)d * 1024 + h * 64 + lq * 16;
  #pragma unroll
  for (int j = 0; j < 16; ++j){
    int lc = lq * 16 + j;
    float acc = 0.f;
    #pragma unroll
    for (int dd = 0; dd < 64; ++dd) acc += wqr[dd] * wc[dd * 64 + lc];
    outp[j] = acc;
  }
}

__global__ void build_bqc(const float* __restrict__ bq, const float* __restrict__ Wc,
                          float* __restrict__ bqc){
  int n = blockIdx.x * 256 + threadIdx.x;
  int h = n >> 6, lc = n & 63;
  float acc = 0.f;
  for (int dd = 0; dd < 64; ++dd) acc += bq[h * 64 + dd] * Wc[dd * 64 + lc];
  bqc[n] = acc;
}

// all four 1024x1024 weight transposes (f32 -> bf16, out[c][r] = in[r][c]) in one dispatch
__global__ void transpose_w4(const float* __restrict__ s0, const float* __restrict__ s1,
                             const float* __restrict__ s2, const float* __restrict__ s3,
                             u16* __restrict__ o0, u16* __restrict__ o1,
                             u16* __restrict__ o2, u16* __restrict__ o3){
  const int z = blockIdx.z;
  const float* in = (z == 0) ? s0 : (z == 1) ? s1 : (z == 2) ? s2 : s3;
  u16* out = (z == 0) ? o0 : (z == 1) ? o1 : (z == 2) ? o2 : o3;
  __shared__ float t[32][33];
  int tx = threadIdx.x & 31, ty = threadIdx.x >> 5;
  int c0 = blockIdx.x * 32, r0 = blockIdx.y * 32;
  #pragma unroll
  for (int i = 0; i < 32; i += 8)
    t[ty + i][tx] = in[(size_t)(r0 + ty + i) * 1024 + c0 + tx];
  __syncthreads();
  #pragma unroll
  for (int i = 0; i < 32; i += 8)
    out[(size_t)(c0 + ty + i) * 1024 + r0 + tx] = f2b(t[tx][ty + i]);
}

// vt[bh][d][s] = vb[b*T + s][h*64 + d]   (bf16 -> bf16 transpose per head)
__global__ void transpose_v(const u16* __restrict__ vb, u16* __restrict__ vt){
  __shared__ u16 t[32][34];
  int tx = threadIdx.x & 31, ty = threadIdx.x >> 5;
  int s0 = blockIdx.x * 32, d0 = blockIdx.y * 32, bh = blockIdx.z;
  int b = bh >> 4, h = bh & 15;
  #pragma unroll
  for (int i = 0; i < 32; i += 8)
    t[ty + i][tx] = vb[(size_t)(b * TT + s0 + ty + i) * 1024 + h * 64 + d0 + tx];
  __syncthreads();
  #pragma unroll
  for (int i = 0; i < 32; i += 8)
    vt[((size_t)bh * 64 + d0 + ty + i) * TT + s0 + tx] = t[tx][ty + i];
}

// ---------------- 128x128 bf16 MFMA GEMM tile (m97 structure) ----------------
__device__ __forceinline__ void gemm_tile(const u16* __restrict__ A, const u16* __restrict__ BT,
                                          int m0, int n0, int K, f32x4 (&acc)[4][4],
                                          u16* As, u16* Bs, int tid){
  const int wv = tid >> 6, l = tid & 63;
  const int aoff = ((wv >> 1) * 64 + (l & 15)) * 32 + ((l >> 4) << 3);
  const int boff = ((wv & 1) * 64 + (l & 15)) * 32 + ((l >> 4) << 3);
  const int ob0 = wv * 1024 + l * 16;           // byte offset in 8KB tile
  for (int kt = 0; kt < K; kt += 32){
    __syncthreads();
    #pragma unroll
    for (int j = 0; j < 2; ++j){
      int ob = ob0 + j * 4096;
      int row = ob >> 6, col = (ob & 63) >> 1;  // col in elements (mult of 8)
      __builtin_amdgcn_global_load_lds((GLOBAL_AS)(A + (size_t)(m0 + row) * 1024 + kt + col),
                                       (LDS_AS)(As + wv * 512 + j * 2048), 16, 0, 0);
      __builtin_amdgcn_global_load_lds((GLOBAL_AS)(BT + (size_t)(n0 + row) * 1024 + kt + col),
                                       (LDS_AS)(Bs + wv * 512 + j * 2048), 16, 0, 0);
    }
    __syncthreads();
    bf16x8 av[4], bw[4];
    #pragma unroll
    for (int m = 0; m < 4; ++m) av[m] = *(const bf16x8*)(As + aoff + m * 512);
    #pragma unroll
    for (int n = 0; n < 4; ++n) bw[n] = *(const bf16x8*)(Bs + boff + n * 512);
    #pragma unroll
    for (int m = 0; m < 4; ++m)
      #pragma unroll
      for (int n = 0; n < 4; ++n)
        acc[m][n] = __builtin_amdgcn_mfma_f32_16x16x32_bf16(av[m], bw[n], acc[m][n], 0, 0, 0);
  }
}

__global__ __launch_bounds__(256) void gemm_qkv(
    const u16* __restrict__ xb,
    const u16* __restrict__ W0T, const u16* __restrict__ W1T, const u16* __restrict__ W2T,
    const float* __restrict__ b0, const float* __restrict__ b1, const float* __restrict__ b2,
    u16* __restrict__ o0, u16* __restrict__ o1, u16* __restrict__ o2){
  __shared__ u16 As[4096], Bs[4096];
  const int z = blockIdx.z;
  const u16* BT = (z == 0) ? W0T : (z == 1) ? W1T : W2T;
  const float* bias = (z == 0) ? b0 : (z == 1) ? b1 : b2;
  u16* Out = (z == 0) ? o0 : (z == 1) ? o1 : o2;
  const int n0 = blockIdx.x * 128, m0 = blockIdx.y * 128;
  const int tid = threadIdx.x, wv = tid >> 6, l = tid & 63;
  f32x4 acc[4][4] = {};
  gemm_tile(xb, BT, m0, n0, 1024, acc, As, Bs, tid);
  const int wr = wv >> 1, wc = wv & 1;
  #pragma unroll
  for (int n = 0; n < 4; ++n){
    int col = n0 + wc * 64 + n * 16 + (l & 15);
    float bb = bias[col];
    #pragma unroll
    for (int m = 0; m < 4; ++m){
      int r0 = m0 + wr * 64 + m * 16 + ((l >> 4) << 2);
      #pragma unroll
      for (int r = 0; r < 4; ++r)
        Out[(size_t)(r0 + r) * 1024 + col] = f2b(acc[m][n][r] + bb);
    }
  }
}

__global__ __launch_bounds__(256) void gemm_fp32out(
    const u16* __restrict__ A, const u16* __restrict__ BT,
    const float* __restrict__ bias, float* __restrict__ Out){
  __shared__ u16 As[4096], Bs[4096];
  const int n0 = blockIdx.x * 128, m0 = blockIdx.y * 128;
  const int tid = threadIdx.x, wv = tid >> 6, l = tid & 63;
  f32x4 acc[4][4] = {};
  gemm_tile(A, BT, m0, n0, 1024, acc, As, Bs, tid);
  const int wr = wv >> 1, wc = wv & 1;
  #pragma unroll
  for (int n = 0; n < 4; ++n){
    int col = n0 + wc * 64 + n * 16 + (l & 15);
    float bb = bias[col];
    #pragma unroll
    for (int m = 0; m < 4; ++m){
      int r0 = m0 + wr * 64 + m * 16 + ((l >> 4) << 2);
      #pragma unroll
      for (int r = 0; r < 4; ++r)
        Out[(size_t)(r0 + r) * 1024 + col] = acc[m][n][r] + bb;
    }
  }
}

// ---------------- flash attention (causal, per (b,h)) ----------------
// BQ=128 (8 waves x 16 q-rows), BS=64, double-buffered staging, swapped QK^T
// (S^T = K Q^T) so softmax rows are lane-local. grid: 512 blocks, heavy-first.
__global__ __launch_bounds__(512) void attn(
    const u16* __restrict__ qcg, const u16* __restrict__ kg,
    const u16* __restrict__ vtg, u16* __restrict__ yg){
  __shared__ u16 Ks[2][4096], Vs[2][4096];   // [64 rows][8 chunks of 16B], XOR-swizzled
  __shared__ u16 Ps[8 * 16 * 72];            // per-wave 16 q-rows x 64 s (+8 pad)
  const int idx = blockIdx.x;
  const int qt = 15 - (idx >> 5), bh = idx & 31;
  const int b = bh >> 4, h = bh & 15;
  const int q0 = qt * 128;
  const int tid = threadIdx.x, wv = tid >> 6, l = tid & 63;
  const int c4 = l >> 4;
  const size_t base = (size_t)b * TT * 1024 + h * 64;
  const u16* Q = qcg + base;
  const u16* K = kg + base;
  const u16* Vt = vtg + (size_t)bh * 64 * TT;     // [64 d][T s]

  // staging source (pre-swizzled so linear LDS == swizzled layout, m173 pattern)
  const int sr = tid >> 3;                         // tile row 0..63
  const int sc = (tid & 7) ^ (sr & 7);             // global 16B-chunk for this slot
  const u16* gK = K + (size_t)sr * 1024 + sc * 8;
  const u16* gV = Vt + (size_t)sr * TT + sc * 8;

  // prologue: stage tile 0 into buffer 0
  __builtin_amdgcn_global_load_lds((GLOBAL_AS)gK, (LDS_AS)(&Ks[0][0] + wv * 512), 16, 0, 0);
  __builtin_amdgcn_global_load_lds((GLOBAL_AS)gV, (LDS_AS)(&Vs[0][0] + wv * 512), 16, 0, 0);

  // Q fragments in registers: 16 q-rows per wave (B-operand: col=q at l&15)
  bf16x8 qf[2];
  {
    int qr = q0 + wv * 16 + (l & 15);
    #pragma unroll
    for (int ks = 0; ks < 2; ++ks)
      qf[ks] = *(const bf16x8*)(Q + (size_t)qr * 1024 + ks * 32 + (c4 << 3));
  }
  f32x4 yacc[4] = {};
  float mrow = -1e30f, srow = 0.f;     // per-lane softmax state for q = l&15

  const int nt = 2 * qt + 2;
  for (int st = 0; st < nt; ++st){
    const int cur = st & 1;
    const u16* Kc = &Ks[cur][0];
    const u16* Vc = &Vs[cur][0];
    if (st + 1 < nt){
      const int s1 = (st + 1) * 64;
      __builtin_amdgcn_global_load_lds((GLOBAL_AS)(gK + (size_t)s1 * 1024),
                                       (LDS_AS)(&Ks[cur ^ 1][0] + wv * 512), 16, 0, 0);
      __builtin_amdgcn_global_load_lds((GLOBAL_AS)(gV + s1),
                                       (LDS_AS)(&Vs[cur ^ 1][0] + wv * 512), 16, 0, 0);
      asm volatile("s_waitcnt vmcnt(2)" ::: "memory");
    } else {
      asm volatile("s_waitcnt vmcnt(0)" ::: "memory");
    }
    __builtin_amdgcn_sched_barrier(0);
    __builtin_amdgcn_s_barrier();
    __builtin_amdgcn_sched_barrier(0);
    const int s0 = st * 64;
    // S^T = K Q^T  (rows=s, cols=q): lane holds 16 s-values for q = l&15
    f32x4 sf[4] = {};
    __builtin_amdgcn_s_setprio(1);
    #pragma unroll
    for (int ks = 0; ks < 2; ++ks)
      #pragma unroll
      for (int nf = 0; nf < 4; ++nf){
        int r = nf * 16 + (l & 15), c = ks * 4 + c4;
        bf16x8 kf = *(const bf16x8*)(Kc + (r * 8 + (c ^ (r & 7))) * 8);
        sf[nf] = __builtin_amdgcn_mfma_f32_16x16x32_bf16(kf, qf[ks], sf[nf], 0, 0, 0);
      }
    __builtin_amdgcn_s_setprio(0);
    // scale into log2 domain + causal mask; s = s0 + 16nf + 4c4 + r
    const int qa = q0 + wv * 16 + (l & 15);
    float p[4][4];
    const bool domask = (s0 + 63 > q0 + wv * 16);
    #pragma unroll
    for (int nf = 0; nf < 4; ++nf)
      #pragma unroll
      for (int r = 0; r < 4; ++r){
        float v_ = sf[nf][r] * LSCALE;
        if (domask && (s0 + nf * 16 + c4 * 4 + r > qa)) v_ = -1e30f;
        p[nf][r] = v_;
      }
    // lane-local row max + quadrant combine
    float tmax = p[0][0];
    #pragma unroll
    for (int nf = 0; nf < 4; ++nf)
      #pragma unroll
      for (int r = 0; r < 4; ++r) tmax = fmaxf(tmax, p[nf][r]);
    tmax = fmaxf(tmax, __shfl_xor(tmax, 16));
    tmax = fmaxf(tmax, __shfl_xor(tmax, 32));
    // defer-max: rescale only when max grew by > 8 (factor 256 headroom in bf16)
    if (__any(tmax > mrow + 8.0f)){
      float mnew = fmaxf(mrow, tmax);
      float resc = exp2f(mrow - mnew);
      srow *= resc;
      mrow = mnew;
      float rq[4];
      #pragma unroll
      for (int r = 0; r < 4; ++r) rq[r] = __shfl(resc, (l & 48) | (c4 * 4 + r));
      #pragma unroll
      for (int df = 0; df < 4; ++df)
        #pragma unroll
        for (int r = 0; r < 4; ++r) yacc[df][r] *= rq[r];
    }
    float tsum = 0.f;
    #pragma unroll
    for (int nf = 0; nf < 4; ++nf)
      #pragma unroll
      for (int r = 0; r < 4; ++r){ float e = exp2f(p[nf][r] - mrow); p[nf][r] = e; tsum += e; }
    tsum += __shfl_xor(tsum, 16);
    tsum += __shfl_xor(tsum, 32);
    srow += tsum;
    // pack P (pairs along s) -> wave-private LDS rows q = l&15
    {
      uint32_t* dst = (uint32_t*)(Ps + wv * 1152 + (l & 15) * 72);
      #pragma unroll
      for (int nf = 0; nf < 4; ++nf){
        uint32_t w0, w1;
        asm volatile("v_cvt_pk_bf16_f32 %0, %1, %2" : "=v"(w0) : "v"(p[nf][0]), "v"(p[nf][1]));
        asm volatile("v_cvt_pk_bf16_f32 %0, %1, %2" : "=v"(w1) : "v"(p[nf][2]), "v"(p[nf][3]));
        *(uint64_t*)(dst + nf * 8 + c4 * 2) = (uint64_t)w0 | ((uint64_t)w1 << 32);
      }
    }
    asm volatile("s_waitcnt lgkmcnt(0)" ::: "memory");
    __builtin_amdgcn_sched_barrier(0);
    // PV: y += P @ V   (A = P rows q at l&15; B = V^T rows d)
    __builtin_amdgcn_s_setprio(1);
    #pragma unroll
    for (int ks2 = 0; ks2 < 2; ++ks2){
      bf16x8 pf = *(const bf16x8*)(Ps + wv * 1152 + (l & 15) * 72 + ks2 * 32 + c4 * 8);
      #pragma unroll
      for (int df = 0; df < 4; ++df){
        int rd = df * 16 + (l & 15), cd = ks2 * 4 + c4;
        bf16x8 vf = *(const bf16x8*)(Vc + (rd * 8 + (cd ^ (rd & 7))) * 8);
        yacc[df] = __builtin_amdgcn_mfma_f32_16x16x32_bf16(pf, vf, yacc[df], 0, 0, 0);
      }
    }
    __builtin_amdgcn_s_setprio(0);
    __builtin_amdgcn_s_barrier();
  }
  // epilogue: yacc rows q = 4*c4 + r need srow from lane (l&48)|q
  float sq[4];
  #pragma unroll
  for (int r = 0; r < 4; ++r) sq[r] = __shfl(srow, (l & 48) | (c4 * 4 + r));
  #pragma unroll
  for (int df = 0; df < 4; ++df){
    int d = df * 16 + (l & 15);
    int qq = q0 + wv * 16 + c4 * 4;
    #pragma unroll
    for (int r = 0; r < 4; ++r){
      float val = yacc[df][r] / sq[r];
      yg[(size_t)(b * TT + qq + r) * 1024 + h * 64 + d] = f2b(val);
    }
  }
}

// ---------------- host ----------------
extern "C" void kernel_launch(void* const* d_in, const int* in_sizes, int n_in,
                              void* d_out, int out_size, void* d_ws, size_t ws_size,
                              hipStream_t stream){
  (void)in_sizes; (void)n_in; (void)out_size; (void)ws_size;
  const float* x  = (const float*)d_in[0];
  const float* Wq = (const float*)d_in[1];
  const float* bq = (const float*)d_in[2];
  const float* Wk = (const float*)d_in[3];
  const float* bk = (const float*)d_in[4];
  const float* Wv = (const float*)d_in[5];
  const float* bv = (const float*)d_in[6];
  const float* Wo = (const float*)d_in[7];
  const float* bo = (const float*)d_in[8];
  const float* Wc = (const float*)d_in[9];
  float* out = (float*)d_out;

  char* wsb = (char*)d_ws;
  u16* xb    = (u16*)(wsb);              // 8MB; dead after gemm_qkv
  u16* yb    = (u16*)(wsb);              // reuses xb region (written by attn, after)
  u16* qcb   = (u16*)(wsb + (8u  << 20));
  u16* kb    = (u16*)(wsb + (16u << 20));
  u16* vb    = (u16*)(wsb + (24u << 20));
  u16* vtb   = (u16*)(wsb + (32u << 20));
  u16* WqcT  = (u16*)(wsb + (40u << 20));
  u16* WkT   = (u16*)(wsb + (42u << 20));
  u16* WvT   = (u16*)(wsb + (44u << 20));
  u16* WoT   = (u16*)(wsb + (46u << 20));
  float* bqc  = (float*)(wsb + (48u << 20));
  float* Wqcf = (float*)(wsb + (48u << 20) + 8192);

  cvt_bf16<<<4096, 256, 0, stream>>>(x, xb, MROWS * 1024 / 4);
  build_wqc<<<256, 256, 0, stream>>>(Wq, Wc, Wqcf);
  build_bqc<<<4, 256, 0, stream>>>(bq, Wc, bqc);
  transpose_w4<<<dim3(32, 32, 4), 256, 0, stream>>>(Wqcf, Wk, Wv, Wo, WqcT, WkT, WvT, WoT);
  gemm_qkv<<<dim3(8, 32, 3), 256, 0, stream>>>(xb, WqcT, WkT, WvT, bqc, bk, bv, qcb, kb, vb);
  transpose_v<<<dim3(64, 2, 32), 256, 0, stream>>>(vb, vtb);
  attn<<<dim3(512), 512, 0, stream>>>(qcb, kb, vtb, yb);
  gemm_fp32out<<<dim3(8, 32), 256, 0, stream>>>(yb, WoT, bo, out);
}

// Round 5
// 131.432 us; speedup vs baseline: 2.0609x; 1.0724x over previous
//
#include <hip/hip_runtime.h>
#include <stdint.h>

#define TT 2048
#define BB 2
#define MROWS (BB*TT)
#define LSCALE 0.18033688011112043f   // 0.125 * log2(e)

typedef unsigned short u16;
typedef __bf16 bf16x8 __attribute__((ext_vector_type(8)));
typedef float f32x4 __attribute__((ext_vector_type(4)));
typedef short s16x8 __attribute__((ext_vector_type(8)));
typedef unsigned short u16x4 __attribute__((ext_vector_type(4)));

#define GLOBAL_AS const __attribute__((address_space(1))) void*
#define LDS_AS __attribute__((address_space(3))) void*

__device__ __forceinline__ u16 f2b(float f){
  uint32_t u = __builtin_bit_cast(uint32_t, f);
  u = (u + 0x7FFFu + ((u >> 16) & 1u)) >> 16;
  return (u16)u;
}

// ---------------- prep kernels ----------------
__global__ void cvt_bf16(const float* __restrict__ in, u16* __restrict__ out, int n4){
  int i = blockIdx.x * 256 + threadIdx.x;
  if (i < n4){
    float4 v = ((const float4*)in)[i];
    u16x4 o; o.x = f2b(v.x); o.y = f2b(v.y); o.z = f2b(v.z); o.w = f2b(v.w);
    ((u16x4*)out)[i] = o;
  }
}

// Wqc[d][h*64+lc] = sum_dd Wq[d][h*64+dd] * Wc[dd][lc]  (fold Wc into Wq)
__global__ __launch_bounds__(256) void build_wqc(const float* __restrict__ Wq,
                                                 const float* __restrict__ Wc,
                                                 float* __restrict__ Wqc){
  __shared__ float wc[4096];
  const int t = threadIdx.x;
  #pragma unroll
  for (int i = 0; i < 16; ++i) wc[i * 256 + t] = Wc[i * 256 + t];
  __syncthreads();
  const int idx = blockIdx.x * 256 + t;   // [0, 65536)
  const int d = idx >> 6;
  const int h = (idx >> 2) & 15;
  const int lq = idx & 3;
  float wqr[64];
  const float4* wq4 = (const float4*)(Wq + (size_t)d * 1024 + h * 64);
  #pragma unroll
  for (int i = 0; i < 16; ++i){
    float4 v = wq4[i];
    wqr[i * 4 + 0] = v.x; wqr[i * 4 + 1] = v.y; wqr[i * 4 + 2] = v.z; wqr[i * 4 + 3] = v.w;
  }
  float* outp = Wqc + (size_t)d * 1024 + h * 64 + lq * 16;
  #pragma unroll
  for (int j = 0; j < 16; ++j){
    int lc = lq * 16 + j;
    float acc = 0.f;
    #pragma unroll
    for (int dd = 0; dd < 64; ++dd) acc += wqr[dd] * wc[dd * 64 + lc];
    outp[j] = acc;
  }
}

__global__ void build_bqc(const float* __restrict__ bq, const float* __restrict__ Wc,
                          float* __restrict__ bqc){
  int n = blockIdx.x * 256 + threadIdx.x;
  int h = n >> 6, lc = n & 63;
  float acc = 0.f;
  for (int dd = 0; dd < 64; ++dd) acc += bq[h * 64 + dd] * Wc[dd * 64 + lc];
  bqc[n] = acc;
}

// all four 1024x1024 weight transposes (f32 -> bf16, out[c][r] = in[r][c]) in one dispatch
__global__ void transpose_w4(const float* __restrict__ s0, const float* __restrict__ s1,
                             const float* __restrict__ s2, const float* __restrict__ s3,
                             u16* __restrict__ o0, u16* __restrict__ o1,
                             u16* __restrict__ o2, u16* __restrict__ o3){
  const int z = blockIdx.z;
  const float* in = (z == 0) ? s0 : (z == 1) ? s1 : (z == 2) ? s2 : s3;
  u16* out = (z == 0) ? o0 : (z == 1) ? o1 : (z == 2) ? o2 : o3;
  __shared__ float t[32][33];
  int tx = threadIdx.x & 31, ty = threadIdx.x >> 5;
  int c0 = blockIdx.x * 32, r0 = blockIdx.y * 32;
  #pragma unroll
  for (int i = 0; i < 32; i += 8)
    t[ty + i][tx] = in[(size_t)(r0 + ty + i) * 1024 + c0 + tx];
  __syncthreads();
  #pragma unroll
  for (int i = 0; i < 32; i += 8)
    out[(size_t)(c0 + ty + i) * 1024 + r0 + tx] = f2b(t[tx][ty + i]);
}

// vt[bh][d][s] = vb[b*T + s][h*64 + d]   (bf16 -> bf16 transpose per head)
__global__ void transpose_v(const u16* __restrict__ vb, u16* __restrict__ vt){
  __shared__ u16 t[32][34];
  int tx = threadIdx.x & 31, ty = threadIdx.x >> 5;
  int s0 = blockIdx.x * 32, d0 = blockIdx.y * 32, bh = blockIdx.z;
  int b = bh >> 4, h = bh & 15;
  #pragma unroll
  for (int i = 0; i < 32; i += 8)
    t[ty + i][tx] = vb[(size_t)(b * TT + s0 + ty + i) * 1024 + h * 64 + d0 + tx];
  __syncthreads();
  #pragma unroll
  for (int i = 0; i < 32; i += 8)
    vt[((size_t)bh * 64 + d0 + ty + i) * TT + s0 + tx] = t[tx][ty + i];
}

// ---------------- 128x128 bf16 MFMA GEMM tile (m97 structure) ----------------
__device__ __forceinline__ void gemm_tile(const u16* __restrict__ A, const u16* __restrict__ BT,
                                          int m0, int n0, int K, f32x4 (&acc)[4][4],
                                          u16* As, u16* Bs, int tid){
  const int wv = tid >> 6, l = tid & 63;
  const int aoff = ((wv >> 1) * 64 + (l & 15)) * 32 + ((l >> 4) << 3);
  const int boff = ((wv & 1) * 64 + (l & 15)) * 32 + ((l >> 4) << 3);
  const int ob0 = wv * 1024 + l * 16;           // byte offset in 8KB tile
  for (int kt = 0; kt < K; kt += 32){
    __syncthreads();
    #pragma unroll
    for (int j = 0; j < 2; ++j){
      int ob = ob0 + j * 4096;
      int row = ob >> 6, col = (ob & 63) >> 1;  // col in elements (mult of 8)
      __builtin_amdgcn_global_load_lds((GLOBAL_AS)(A + (size_t)(m0 + row) * 1024 + kt + col),
                                       (LDS_AS)(As + wv * 512 + j * 2048), 16, 0, 0);
      __builtin_amdgcn_global_load_lds((GLOBAL_AS)(BT + (size_t)(n0 + row) * 1024 + kt + col),
                                       (LDS_AS)(Bs + wv * 512 + j * 2048), 16, 0, 0);
    }
    __syncthreads();
    bf16x8 av[4], bw[4];
    #pragma unroll
    for (int m = 0; m < 4; ++m) av[m] = *(const bf16x8*)(As + aoff + m * 512);
    #pragma unroll
    for (int n = 0; n < 4; ++n) bw[n] = *(const bf16x8*)(Bs + boff + n * 512);
    #pragma unroll
    for (int m = 0; m < 4; ++m)
      #pragma unroll
      for (int n = 0; n < 4; ++n)
        acc[m][n] = __builtin_amdgcn_mfma_f32_16x16x32_bf16(av[m], bw[n], acc[m][n], 0, 0, 0);
  }
}

__global__ __launch_bounds__(256) void gemm_qkv(
    const u16* __restrict__ xb,
    const u16* __restrict__ W0T, const u16* __restrict__ W1T, const u16* __restrict__ W2T,
    const float* __restrict__ b0, const float* __restrict__ b1, const float* __restrict__ b2,
    u16* __restrict__ o0, u16* __restrict__ o1, u16* __restrict__ o2){
  __shared__ u16 As[4096], Bs[4096];
  const int z = blockIdx.z;
  const u16* BT = (z == 0) ? W0T : (z == 1) ? W1T : W2T;
  const float* bias = (z == 0) ? b0 : (z == 1) ? b1 : b2;
  u16* Out = (z == 0) ? o0 : (z == 1) ? o1 : o2;
  const float osc = (z == 0) ? LSCALE : 1.0f;   // fold softmax scale into Q
  const int n0 = blockIdx.x * 128, m0 = blockIdx.y * 128;
  const int tid = threadIdx.x, wv = tid >> 6, l = tid & 63;
  f32x4 acc[4][4] = {};
  gemm_tile(xb, BT, m0, n0, 1024, acc, As, Bs, tid);
  const int wr = wv >> 1, wc = wv & 1;
  #pragma unroll
  for (int n = 0; n < 4; ++n){
    int col = n0 + wc * 64 + n * 16 + (l & 15);
    float bb = bias[col];
    #pragma unroll
    for (int m = 0; m < 4; ++m){
      int r0 = m0 + wr * 64 + m * 16 + ((l >> 4) << 2);
      #pragma unroll
      for (int r = 0; r < 4; ++r)
        Out[(size_t)(r0 + r) * 1024 + col] = f2b((acc[m][n][r] + bb) * osc);
    }
  }
}

__global__ __launch_bounds__(256) void gemm_fp32out(
    const u16* __restrict__ A, const u16* __restrict__ BT,
    const float* __restrict__ bias, float* __restrict__ Out){
  __shared__ u16 As[4096], Bs[4096];
  const int n0 = blockIdx.x * 128, m0 = blockIdx.y * 128;
  const int tid = threadIdx.x, wv = tid >> 6, l = tid & 63;
  f32x4 acc[4][4] = {};
  gemm_tile(A, BT, m0, n0, 1024, acc, As, Bs, tid);
  const int wr = wv >> 1, wc = wv & 1;
  #pragma unroll
  for (int n = 0; n < 4; ++n){
    int col = n0 + wc * 64 + n * 16 + (l & 15);
    float bb = bias[col];
    #pragma unroll
    for (int m = 0; m < 4; ++m){
      int r0 = m0 + wr * 64 + m * 16 + ((l >> 4) << 2);
      #pragma unroll
      for (int r = 0; r < 4; ++r)
        Out[(size_t)(r0 + r) * 1024 + col] = acc[m][n][r] + bb;
    }
  }
}

// ---------------- flash attention (causal, per (b,h)) ----------------
// BQ=64 (4 waves x 16 q-rows), BS=64, double-buffered staging, swapped QK^T
// (S^T = K Q^T) so softmax rows are lane-local. grid: 1024 blocks, heavy-first.
// LDS = 32KB (K/V dbuf) + 8KB (Ps) = 40960 B -> 4 blocks/CU.
__global__ __launch_bounds__(256) void attn(
    const u16* __restrict__ qcg, const u16* __restrict__ kg,
    const u16* __restrict__ vtg, u16* __restrict__ yg){
  __shared__ u16 Ks[2][4096], Vs[2][4096];   // [64 rows][8 chunks of 16B], XOR-swizzled
  __shared__ u16 Ps[4 * 16 * 64];            // per-wave 16 q-rows x 64 s, XOR-swizzled dwords
  const int idx = blockIdx.x;
  const int qt = 31 - (idx >> 5), bh = idx & 31;
  const int b = bh >> 4, h = bh & 15;
  const int q0 = qt * 64;
  const int tid = threadIdx.x, wv = tid >> 6, l = tid & 63;
  const int c4 = l >> 4, q16 = l & 15;
  const size_t base = (size_t)b * TT * 1024 + h * 64;
  const u16* Q = qcg + base;
  const u16* K = kg + base;
  const u16* Vt = vtg + (size_t)bh * 64 * TT;     // [64 d][T s]

  // staging source (pre-swizzled so linear LDS == swizzled layout, m173 pattern)
  const int sr = tid >> 3;                         // tile row 0..31 (x2 halves)
  const int sc = (tid & 7) ^ (sr & 7);             // global 16B-chunk for this slot
  const u16* gK = K + (size_t)sr * 1024 + sc * 8;
  const u16* gV = Vt + (size_t)sr * TT + sc * 8;

  // prologue: stage tile 0 into buffer 0 (4 waves x 1KB per inst; 2 insts per tile half)
  __builtin_amdgcn_global_load_lds((GLOBAL_AS)gK, (LDS_AS)(&Ks[0][0] + wv * 512), 16, 0, 0);
  __builtin_amdgcn_global_load_lds((GLOBAL_AS)(gK + 32 * 1024), (LDS_AS)(&Ks[0][0] + 2048 + wv * 512), 16, 0, 0);
  __builtin_amdgcn_global_load_lds((GLOBAL_AS)gV, (LDS_AS)(&Vs[0][0] + wv * 512), 16, 0, 0);
  __builtin_amdgcn_global_load_lds((GLOBAL_AS)(gV + 32 * TT), (LDS_AS)(&Vs[0][0] + 2048 + wv * 512), 16, 0, 0);

  // Q fragments in registers: 16 q-rows per wave (B-operand: col=q at l&15)
  bf16x8 qf[2];
  {
    int qr = q0 + wv * 16 + q16;
    #pragma unroll
    for (int ks = 0; ks < 2; ++ks)
      qf[ks] = *(const bf16x8*)(Q + (size_t)qr * 1024 + ks * 32 + (c4 << 3));
  }
  f32x4 yacc[4] = {};
  float mrow = -1e30f, srow = 0.f;     // per-lane softmax state for q = l&15

  uint32_t* const PsW = (uint32_t*)Ps + wv * 512 + q16 * 32;  // this lane's P row (dwords)
  const int pm = (q16 & 7) << 2;                              // Ps dword-col XOR mask

  const int nt = qt + 1;
  for (int st = 0; st < nt; ++st){
    const int cur = st & 1;
    const u16* Kc = &Ks[cur][0];
    const u16* Vc = &Vs[cur][0];
    if (st + 1 < nt){
      const int s1 = (st + 1) * 64;
      u16* kd = &Ks[cur ^ 1][0] + wv * 512;
      u16* vd = &Vs[cur ^ 1][0] + wv * 512;
      __builtin_amdgcn_global_load_lds((GLOBAL_AS)(gK + (size_t)s1 * 1024), (LDS_AS)kd, 16, 0, 0);
      __builtin_amdgcn_global_load_lds((GLOBAL_AS)(gK + (size_t)(s1 + 32) * 1024), (LDS_AS)(kd + 2048), 16, 0, 0);
      __builtin_amdgcn_global_load_lds((GLOBAL_AS)(gV + s1), (LDS_AS)vd, 16, 0, 0);
      __builtin_amdgcn_global_load_lds((GLOBAL_AS)(gV + s1 + 32 * TT), (LDS_AS)(vd + 2048), 16, 0, 0);
      asm volatile("s_waitcnt vmcnt(4)" ::: "memory");   // cur's 4 loads landed, next's in flight
    } else {
      asm volatile("s_waitcnt vmcnt(0)" ::: "memory");
    }
    __builtin_amdgcn_sched_barrier(0);
    __builtin_amdgcn_s_barrier();
    __builtin_amdgcn_sched_barrier(0);
    const int s0 = st * 64;
    // S^T = K Q^T  (rows=s, cols=q): lane holds 16 s-values for q = l&15
    f32x4 sf[4] = {};
    __builtin_amdgcn_s_setprio(1);
    #pragma unroll
    for (int ks = 0; ks < 2; ++ks)
      #pragma unroll
      for (int nf = 0; nf < 4; ++nf){
        int r = nf * 16 + q16, c = ks * 4 + c4;
        bf16x8 kf = *(const bf16x8*)(Kc + (r * 8 + (c ^ (r & 7))) * 8);
        sf[nf] = __builtin_amdgcn_mfma_f32_16x16x32_bf16(kf, qf[ks], sf[nf], 0, 0, 0);
      }
    __builtin_amdgcn_s_setprio(0);
    // causal mask (diagonal tile only); scores already in log2 domain (Q pre-scaled)
    const int qa = q0 + wv * 16 + q16;
    float p[4][4];
    const bool domask = (st == nt - 1);
    #pragma unroll
    for (int nf = 0; nf < 4; ++nf)
      #pragma unroll
      for (int r = 0; r < 4; ++r){
        float v_ = sf[nf][r];
        if (domask && (s0 + nf * 16 + c4 * 4 + r > qa)) v_ = -1e30f;
        p[nf][r] = v_;
      }
    // lane-local row max + quadrant combine
    float tmax = p[0][0];
    #pragma unroll
    for (int nf = 0; nf < 4; ++nf)
      #pragma unroll
      for (int r = 0; r < 4; ++r) tmax = fmaxf(tmax, p[nf][r]);
    tmax = fmaxf(tmax, __shfl_xor(tmax, 16));
    tmax = fmaxf(tmax, __shfl_xor(tmax, 32));
    // defer-max: rescale only when max grew by > 8 (factor 256 headroom)
    if (__any(tmax > mrow + 8.0f)){
      float mnew = fmaxf(mrow, tmax);
      float resc = exp2f(mrow - mnew);
      srow *= resc;
      mrow = mnew;
      float rq[4];
      #pragma unroll
      for (int r = 0; r < 4; ++r) rq[r] = __shfl(resc, (l & 48) | (c4 * 4 + r));
      #pragma unroll
      for (int df = 0; df < 4; ++df)
        #pragma unroll
        for (int r = 0; r < 4; ++r) yacc[df][r] *= rq[r];
    }
    float tsum = 0.f;
    #pragma unroll
    for (int nf = 0; nf < 4; ++nf)
      #pragma unroll
      for (int r = 0; r < 4; ++r){ float e = exp2f(p[nf][r] - mrow); p[nf][r] = e; tsum += e; }
    tsum += __shfl_xor(tsum, 16);
    tsum += __shfl_xor(tsum, 32);
    srow += tsum;
    // pack P (pairs along s) -> wave-private LDS row q, XOR-swizzled dword cols
    #pragma unroll
    for (int nf = 0; nf < 4; ++nf){
      uint32_t w0, w1;
      asm volatile("v_cvt_pk_bf16_f32 %0, %1, %2" : "=v"(w0) : "v"(p[nf][0]), "v"(p[nf][1]));
      asm volatile("v_cvt_pk_bf16_f32 %0, %1, %2" : "=v"(w1) : "v"(p[nf][2]), "v"(p[nf][3]));
      *(uint64_t*)(PsW + ((nf * 8 + c4 * 2) ^ pm)) = (uint64_t)w0 | ((uint64_t)w1 << 32);
    }
    asm volatile("s_waitcnt lgkmcnt(0)" ::: "memory");
    __builtin_amdgcn_sched_barrier(0);
    // PV: y += P @ V   (A = P rows q at l&15; B = V^T rows d)
    __builtin_amdgcn_s_setprio(1);
    #pragma unroll
    for (int ks2 = 0; ks2 < 2; ++ks2){
      bf16x8 pf = *(const bf16x8*)(PsW + ((ks2 * 16 + c4 * 4) ^ pm));
      #pragma unroll
      for (int df = 0; df < 4; ++df){
        int rd = df * 16 + q16, cd = ks2 * 4 + c4;
        bf16x8 vf = *(const bf16x8*)(Vc + (rd * 8 + (cd ^ (rd & 7))) * 8);
        yacc[df] = __builtin_amdgcn_mfma_f32_16x16x32_bf16(pf, vf, yacc[df], 0, 0, 0);
      }
    }
    __builtin_amdgcn_s_setprio(0);
    __builtin_amdgcn_s_barrier();
  }
  // epilogue: yacc rows q = 4*c4 + r need srow from lane (l&48)|q
  float sq[4];
  #pragma unroll
  for (int r = 0; r < 4; ++r) sq[r] = __shfl(srow, (l & 48) | (c4 * 4 + r));
  #pragma unroll
  for (int df = 0; df < 4; ++df){
    int d = df * 16 + q16;
    int qq = q0 + wv * 16 + c4 * 4;
    #pragma unroll
    for (int r = 0; r < 4; ++r){
      float val = yacc[df][r] / sq[r];
      yg[(size_t)(b * TT + qq + r) * 1024 + h * 64 + d] = f2b(val);
    }
  }
}

// ---------------- host ----------------
extern "C" void kernel_launch(void* const* d_in, const int* in_sizes, int n_in,
                              void* d_out, int out_size, void* d_ws, size_t ws_size,
                              hipStream_t stream){
  (void)in_sizes; (void)n_in; (void)out_size; (void)ws_size;
  const float* x  = (const float*)d_in[0];
  const float* Wq = (const float*)d_in[1];
  const float* bq = (const float*)d_in[2];
  const float* Wk = (const float*)d_in[3];
  const float* bk = (const float*)d_in[4];
  const float* Wv = (const float*)d_in[5];
  const float* bv = (const float*)d_in[6];
  const float* Wo = (const float*)d_in[7];
  const float* bo = (const float*)d_in[8];
  const float* Wc = (const float*)d_in[9];
  float* out = (float*)d_out;

  char* wsb = (char*)d_ws;
  u16* xb    = (u16*)(wsb);              // 8MB; dead after gemm_qkv
  u16* yb    = (u16*)(wsb);              // reuses xb region (written by attn, after)
  u16* qcb   = (u16*)(wsb + (8u  << 20));
  u16* kb    = (u16*)(wsb + (16u << 20));
  u16* vb    = (u16*)(wsb + (24u << 20));
  u16* vtb   = (u16*)(wsb + (32u << 20));
  u16* WqcT  = (u16*)(wsb + (40u << 20));
  u16* WkT   = (u16*)(wsb + (42u << 20));
  u16* WvT   = (u16*)(wsb + (44u << 20));
  u16* WoT   = (u16*)(wsb + (46u << 20));
  float* bqc  = (float*)(wsb + (48u << 20));
  float* Wqcf = (float*)(wsb + (48u << 20) + 8192);

  cvt_bf16<<<4096, 256, 0, stream>>>(x, xb, MROWS * 1024 / 4);
  build_wqc<<<256, 256, 0, stream>>>(Wq, Wc, Wqcf);
  build_bqc<<<4, 256, 0, stream>>>(bq, Wc, bqc);
  transpose_w4<<<dim3(32, 32, 4), 256, 0, stream>>>(Wqcf, Wk, Wv, Wo, WqcT, WkT, WvT, WoT);
  gemm_qkv<<<dim3(8, 32, 3), 256, 0, stream>>>(xb, WqcT, WkT, WvT, bqc, bk, bv, qcb, kb, vb);
  transpose_v<<<dim3(64, 2, 32), 256, 0, stream>>>(vb, vtb);
  attn<<<dim3(1024), 256, 0, stream>>>(qcb, kb, vtb, yb);
  gemm_fp32out<<<dim3(8, 32), 256, 0, stream>>>(yb, WoT, bo, out);
}